// Round 4
// baseline (571.665 us; speedup 1.0000x reference)
//
#include <hip/hip_runtime.h>
#include <hip/hip_bf16.h>

typedef unsigned short u16;
typedef __attribute__((ext_vector_type(4))) float f32x4;
typedef __attribute__((ext_vector_type(8))) short bf16x8;

// ---------------------------------------------------------------------------
// helpers
// ---------------------------------------------------------------------------
__device__ __forceinline__ u16 f2bf(float f) {
    union { float f; unsigned u; } v; v.f = f;
    unsigned r = (v.u + 0x7fffu + ((v.u >> 16) & 1u)) >> 16;   // RNE
    return (u16)r;
}

__device__ __forceinline__ float softplus(float x) {
    return (x > 15.f) ? x : log1pf(__expf(x));
}

__device__ __forceinline__ void gload_lds16(const void* g, void* l) {
    __builtin_amdgcn_global_load_lds(
        (__attribute__((address_space(1))) void*)(g),
        (__attribute__((address_space(3))) void*)(l),
        16, 0, 0);
}

#define BAR() do { asm volatile("" ::: "memory"); \
                   __builtin_amdgcn_s_barrier();  \
                   asm volatile("" ::: "memory"); } while (0)

// ---------------------------------------------------------------------------
// prep kernels (BW-roofline already)
// ---------------------------------------------------------------------------
__global__ __launch_bounds__(256) void prep_x_kernel(
        const float* __restrict__ x, u16* __restrict__ xb, int n4) {
    int i = blockIdx.x * 256 + threadIdx.x;
    if (i >= n4) return;
    float4 v = ((const float4*)x)[i];
    ushort4 o;
    o.x = f2bf(v.x); o.y = f2bf(v.y); o.z = f2bf(v.z); o.w = f2bf(v.w);
    ((ushort4*)xb)[i] = o;
}

__global__ __launch_bounds__(256) void prep_w_kernel(
        const float* __restrict__ mu, const float* __restrict__ rho,
        const float* __restrict__ eps, u16* __restrict__ wb, int n4) {
    int i = blockIdx.x * 256 + threadIdx.x;
    if (i >= n4) return;
    float4 m = ((const float4*)mu)[i];
    float4 r = ((const float4*)rho)[i];
    float4 e = ((const float4*)eps)[i];
    ushort4 o;
    o.x = f2bf(m.x + softplus(r.x) * e.x);
    o.y = f2bf(m.y + softplus(r.y) * e.y);
    o.z = f2bf(m.z + softplus(r.z) * e.z);
    o.w = f2bf(m.w + softplus(r.w) * e.w);
    ((ushort4*)wb)[i] = o;
}

__global__ __launch_bounds__(256) void prep_bias_kernel(
        const float* __restrict__ mu, const float* __restrict__ rho,
        const float* __restrict__ eps, float* __restrict__ b, int n) {
    int i = blockIdx.x * 256 + threadIdx.x;
    if (i < n) b[i] = mu[i] + softplus(rho[i]) * eps[i];
}

// ---------------------------------------------------------------------------
// 256x256 8-phase bf16 GEMM (B^T) + bias — deep pipeline (template depth):
// staging at earliest-legal phases; vmcnt(6) at PH4/PH8 (3 half-tiles flying);
// prologue stages 7 half-tiles. Reads 4/4/8/8 per phase; swizzled LDS.
// ---------------------------------------------------------------------------
__device__ __forceinline__ bf16x8 ld_frag(const u16* region, int r0, int ks, int lane) {
    int row = r0 + (lane & 15);
    int kc  = (ks * 4 + (lane >> 4)) ^ (row & 7);
    return *(const bf16x8*)((const char*)region + row * 128 + kc * 16);
}

template <int MB, int NB>
__device__ __forceinline__ void mfma_quad(f32x4 (&acc)[8][4],
                                          const bf16x8 (&av)[4][2],
                                          const bf16x8 (&bv)[2][2]) {
#pragma unroll
    for (int ks = 0; ks < 2; ++ks)
#pragma unroll
        for (int mi = 0; mi < 4; ++mi)
#pragma unroll
            for (int ni = 0; ni < 2; ++ni)
                acc[MB + mi][NB + ni] = __builtin_amdgcn_mfma_f32_16x16x32_bf16(
                    av[mi][ks], bv[ni][ks], acc[MB + mi][NB + ni], 0, 0, 0);
}

// stage one half-unit (128 rows x 64 k): 2 x global_load_lds(16B) per thread
#define STAGE(region, h, P, koff) do {                                          \
    gload_lds16(P[h][0] + (koff), (char*)(region) + (h) * 16384 + (w * 2 + 0) * 1024); \
    gload_lds16(P[h][1] + (koff), (char*)(region) + (h) * 16384 + (w * 2 + 1) * 1024); \
} while (0)

#define RD_A(reg, roff)                                                \
    _Pragma("unroll")                                                  \
    for (int mi = 0; mi < 4; ++mi)                                     \
        _Pragma("unroll")                                              \
        for (int ks = 0; ks < 2; ++ks)                                 \
            a[mi][ks] = ld_frag(reg, wr * 128 + (roff) + mi * 16, ks, lane)

#define RD_B(dst, reg, roff)                                           \
    _Pragma("unroll")                                                  \
    for (int ni = 0; ni < 2; ++ni)                                     \
        _Pragma("unroll")                                              \
        for (int ks = 0; ks < 2; ++ks)                                 \
            dst[ni][ks] = ld_frag(reg, wc * 64 + (roff) + ni * 16, ks, lane)

__global__ __launch_bounds__(512, 2) void gemm256_8ph(
        const u16* __restrict__ A,   // [M][K] bf16
        const u16* __restrict__ B,   // [Nout][K] bf16
        const float* __restrict__ bias,
        float* __restrict__ C,       // [M][Nout] fp32
        int M, int Nout, int K) {
    __shared__ __attribute__((aligned(16))) u16 smem[4][16384];  // A0,B0,A1,B1
    u16* A0 = smem[0]; u16* B0 = smem[1];
    u16* A1 = smem[2]; u16* B1 = smem[3];

    const int tid  = threadIdx.x;
    const int lane = tid & 63;
    const int w    = tid >> 6;     // wave 0..7
    const int wr   = w >> 2;       // 0..1 -> 128-row slice
    const int wc   = w & 3;        // 0..3 -> 64-col slice

    // bijective XCD swizzle (nwg % 8 == 0 here)
    const int nbn = Nout >> 8;
    const int nwg = (M >> 8) * nbn;
    const int cpx = nwg >> 3;
    const int swz = ((int)blockIdx.x & 7) * cpx + ((int)blockIdx.x >> 3);
    const int m0 = (swz / nbn) << 8;
    const int n0 = (swz % nbn) << 8;

    // per-thread staging source pointers (inverse-swizzled global chunks)
    const u16* PA[2][2]; const u16* PB[2][2];
#pragma unroll
    for (int q = 0; q < 2; ++q) {
        int c   = (w * 2 + q) * 64 + lane;
        int row = c >> 3;
        int kc  = (c & 7) ^ (row & 7);
#pragma unroll
        for (int h = 0; h < 2; ++h) {
            PA[h][q] = A + (size_t)(m0 + h * 128 + row) * K + kc * 8;
            PB[h][q] = B + (size_t)(n0 + h * 128 + row) * K + kc * 8;
        }
    }

    bf16x8 a[4][2], bl[2][2], bh[2][2];
    f32x4 acc[8][4] = {};

    const int NT = K >> 6;    // K-tiles
    const int NI = NT >> 1;   // iterations (2 tiles each)

    // prologue: 7 half-tiles -> tile0 full, B1(t1) full, A1-lo(t1);
    // vmcnt(6) leaves exactly {B1-lo,B1-hi,A1-lo} flying (template depth).
    STAGE(B0, 0, PB, 0);  STAGE(B0, 1, PB, 0);
    STAGE(A0, 0, PA, 0);  STAGE(A0, 1, PA, 0);
    STAGE(B1, 0, PB, 64); STAGE(B1, 1, PB, 64);
    STAGE(A1, 0, PA, 64);
    asm volatile("s_waitcnt vmcnt(6)" ::: "memory");   // tile0 landed
    BAR();
    RD_A(A0, 0);   // al pre-read for PH1 (matches PH8-exit state)

#pragma unroll 1
    for (int i = 0; i < NI; ++i) {
        int t2 = 2 * i + 2; if (t2 >= NT) t2 -= NT;
        int t3 = 2 * i + 3; if (t3 >= NT) t3 -= NT;
        const int k1 = (2 * i + 1) << 6;
        const int k2 = t2 << 6;
        const int k3 = t3 << 6;

        // ---- PH1: q0 = al x bl           | reads bl(4) | stage A1-hi(t1)
        RD_B(bl, B0, 0);
        STAGE(A1, 1, PA, k1);
        BAR();
        asm volatile("s_waitcnt lgkmcnt(0)" ::: "memory");
        __builtin_amdgcn_s_setprio(1);
        mfma_quad<0, 0>(acc, a, bl);
        __builtin_amdgcn_s_setprio(0);
        BAR();

        // ---- PH2: q1 = al x bh           | reads bh(4)
        RD_B(bh, B0, 32);
        BAR();
        asm volatile("s_waitcnt lgkmcnt(0)" ::: "memory");
        __builtin_amdgcn_s_setprio(1);
        mfma_quad<0, 2>(acc, a, bh);
        __builtin_amdgcn_s_setprio(0);
        BAR();

        // ---- PH3: q2 = ah x bh           | reads ah(8) | stage B0-lo(t2)
        RD_A(A0, 64);
        STAGE(B0, 0, PB, k2);
        BAR();
        asm volatile("s_waitcnt lgkmcnt(0)" ::: "memory");
        __builtin_amdgcn_s_setprio(1);
        mfma_quad<4, 2>(acc, a, bh);
        __builtin_amdgcn_s_setprio(0);
        BAR();

        // ---- PH4: q3 = ah x bl | stage B0-hi(t2)+A0-lo(t2) | vmcnt(6): A1(t1) landed
        //      then read al'(8) from A1 under q3's MFMA drain
        STAGE(B0, 1, PB, k2);
        STAGE(A0, 0, PA, k2);
        asm volatile("s_waitcnt vmcnt(6)" ::: "memory");
        BAR();
        __builtin_amdgcn_s_setprio(1);
        mfma_quad<4, 0>(acc, a, bl);
        __builtin_amdgcn_s_setprio(0);
        RD_A(A1, 0);
        BAR();

        // ---- PH5: q0' = al' x bl'        | reads bl'(4) | stage A0-hi(t2)
        RD_B(bl, B1, 0);
        STAGE(A0, 1, PA, k2);
        BAR();
        asm volatile("s_waitcnt lgkmcnt(0)" ::: "memory");
        __builtin_amdgcn_s_setprio(1);
        mfma_quad<0, 0>(acc, a, bl);
        __builtin_amdgcn_s_setprio(0);
        BAR();

        // ---- PH6: q1' = al' x bh'        | reads bh'(4)
        RD_B(bh, B1, 32);
        BAR();
        asm volatile("s_waitcnt lgkmcnt(0)" ::: "memory");
        __builtin_amdgcn_s_setprio(1);
        mfma_quad<0, 2>(acc, a, bh);
        __builtin_amdgcn_s_setprio(0);
        BAR();

        // ---- PH7: q2' = ah' x bh'        | reads ah'(8) | stage B1-lo(t3)
        RD_A(A1, 64);
        STAGE(B1, 0, PB, k3);
        BAR();
        asm volatile("s_waitcnt lgkmcnt(0)" ::: "memory");
        __builtin_amdgcn_s_setprio(1);
        mfma_quad<4, 2>(acc, a, bh);
        __builtin_amdgcn_s_setprio(0);
        BAR();

        // ---- PH8: q3' = ah' x bl' | stage B1-hi(t3)+A1-lo(t3) | vmcnt(6):
        //      B0(t2)+A0(t2) landed; then read al''(8) from A0 for next PH1
        STAGE(B1, 1, PB, k3);
        STAGE(A1, 0, PA, k3);
        asm volatile("s_waitcnt vmcnt(6)" ::: "memory");
        BAR();
        __builtin_amdgcn_s_setprio(1);
        mfma_quad<4, 0>(acc, a, bl);
        __builtin_amdgcn_s_setprio(0);
        RD_A(A0, 0);
        BAR();
    }

    asm volatile("s_waitcnt vmcnt(0)" ::: "memory");  // drain wrapped prefetch

    // epilogue: C/D layout col = lane&15, row = (lane>>4)*4 + q
    const int crow = (lane >> 4) * 4;
    const int ccol = lane & 15;
#pragma unroll
    for (int mi = 0; mi < 8; ++mi) {
#pragma unroll
        for (int ni = 0; ni < 4; ++ni) {
            const int row = m0 + wr * 128 + mi * 16 + crow;
            const int col = n0 + wc * 64 + ni * 16 + ccol;
            const float bv = bias[col];
            float* Cp = C + (size_t)row * Nout + col;
#pragma unroll
            for (int q = 0; q < 4; ++q)
                Cp[(size_t)q * Nout] = acc[mi][ni][q] + bv;
        }
    }
}

// ---------------------------------------------------------------------------
// launch
// ---------------------------------------------------------------------------
extern "C" void kernel_launch(void* const* d_in, const int* in_sizes, int n_in,
                              void* d_out, int out_size, void* d_ws, size_t ws_size,
                              hipStream_t stream) {
    const float* x    = (const float*)d_in[0];
    const float* wmu  = (const float*)d_in[1];
    const float* wrho = (const float*)d_in[2];
    const float* bmu  = (const float*)d_in[3];
    const float* brho = (const float*)d_in[4];
    const float* ew   = (const float*)d_in[5];
    const float* eb   = (const float*)d_in[6];
    float* out = (float*)d_out;

    const int Nout = in_sizes[3];            // 4096
    const int K    = in_sizes[1] / Nout;     // 4096
    const int M    = in_sizes[0] / K;        // 16384

    u16* xb = (u16*)d_ws;
    u16* wb = xb + (size_t)M * K;
    float* bs = (float*)(wb + (size_t)Nout * K);

    const int nx4 = (M * K) / 4;
    const int nw4 = (Nout * K) / 4;
    prep_x_kernel<<<(nx4 + 255) / 256, 256, 0, stream>>>(x, xb, nx4);
    prep_w_kernel<<<(nw4 + 255) / 256, 256, 0, stream>>>(wmu, wrho, ew, wb, nw4);
    prep_bias_kernel<<<(Nout + 255) / 256, 256, 0, stream>>>(bmu, brho, eb, bs, Nout);

    dim3 grid((M / 256) * (Nout / 256));
    gemm256_8ph<<<grid, 512, 0, stream>>>(xb, wb, bs, out, M, Nout, K);
}